// Round 6
// baseline (259.930 us; speedup 1.0000x reference)
//
#include <hip/hip_runtime.h>
#include <math.h>

#define B 16
#define N 10000
#define E 160000
#define CAP 96   // per-dst bucket capacity; deg ~ Poisson(16), P(deg>96) ~ 0

// float -> bf16 (RNE) stored as ushort
__device__ __forceinline__ ushort f2bf(float v) {
    uint u = __float_as_uint(v);
    u = (u + 0x7fffu + ((u >> 16) & 1u)) >> 16;
    return (ushort)u;
}
__device__ __forceinline__ float bf2f(ushort u) { return __uint_as_float(((uint)u) << 16); }
__device__ __forceinline__ float bf2f_lo(uint u) { return __uint_as_float(u << 16); }
__device__ __forceinline__ float bf2f_hi(uint u) { return __uint_as_float(u & 0xffff0000u); }

// ---------------------------------------------------------------------------
// Prep: X (B,N,32) fp32 -> xt (N,B,32) bf16, plus layer-1 gate dots (fp32).
// ---------------------------------------------------------------------------
__global__ void prep_kernel(const float* __restrict__ X,
                            const float* __restrict__ gate_w,   // (65)
                            ushort* __restrict__ xt,
                            float* __restrict__ gi, float* __restrict__ gj) {
    int t = blockIdx.x * blockDim.x + threadIdx.x;
    if (t >= N * B * 32) return;
    int c = t & 31;
    int r = t >> 5;            // n*B + b
    int b = r & 15;
    int n = r >> 4;
    float v = X[((size_t)b * N + n) * 32 + c];
    xt[t] = f2bf(v);
    float pi = v * gate_w[c];
    float pj = v * gate_w[32 + c];
    #pragma unroll
    for (int off = 16; off; off >>= 1) {
        pi += __shfl_xor(pi, off, 32);
        pj += __shfl_xor(pj, off, 32);
    }
    if (c == 0) { gi[r] = pi; gj[r] = pj; }
}

// ---------------------------------------------------------------------------
// Bucket both graphs: payload = src only; slotof[e] = bucket slot (or -1).
// ---------------------------------------------------------------------------
__global__ void bucket_kernel(const int* __restrict__ ei1, const int* __restrict__ ei2,
                              int* __restrict__ bcount1, int* __restrict__ bucket1,
                              int* __restrict__ slot1,
                              int* __restrict__ bcount2, int* __restrict__ bucket2,
                              int* __restrict__ slot2) {
    int t = blockIdx.x * blockDim.x + threadIdx.x;
    if (t < E) {
        int d = ei1[E + t];
        int pos = atomicAdd(&bcount1[d], 1);
        if (pos < CAP) { bucket1[d * CAP + pos] = ei1[t]; slot1[t] = d * CAP + pos; }
        else slot1[t] = -1;
    } else if (t < 2 * E) {
        int e = t - E;
        int d = ei2[E + e];
        int pos = atomicAdd(&bcount2[d], 1);
        if (pos < CAP) { bucket2[d * CAP + pos] = ei2[e]; slot2[e] = d * CAP + pos; }
        else slot2[e] = -1;
    }
}

// ---------------------------------------------------------------------------
// Edge-parallel coefficient precompute: 16 threads per edge (one per batch).
//   cbuf[slot*16+b] = bf16( ew * sigmoid(gi[dst,b] + gj[src,b] + ew*wge + gb) )
// ---------------------------------------------------------------------------
__global__ void coef_kernel(const int* __restrict__ src, const int* __restrict__ dst,
                            const float* __restrict__ ew,
                            const float* __restrict__ gi, const float* __restrict__ gj,
                            const int* __restrict__ slot,
                            const float* __restrict__ gate_w, int wge_idx,
                            const float* __restrict__ gate_b,
                            ushort* __restrict__ cbuf) {
    int t = blockIdx.x * blockDim.x + threadIdx.x;
    int e = t >> 4, b = t & 15;
    if (e >= E) return;
    int sl = slot[e];
    if (sl < 0) return;
    float w = ew[e];
    float z = gi[dst[e] * 16 + b] + gj[src[e] * 16 + b] + w * gate_w[wge_idx] + gate_b[0];
    float c = w / (1.0f + __expf(-z));
    cbuf[sl * 16 + b] = f2bf(c);
}

// ---------------------------------------------------------------------------
// Fused layer 1, node split across 2 blocks (8 batches each). 256 threads.
// Gather: 16 lanes x bf16x2 per row, 2-way k-parallel, 8-deep unroll.
// ---------------------------------------------------------------------------
__global__ __launch_bounds__(256)
void agg_dense1_kernel(const float* __restrict__ X,
                       const uint* __restrict__ xt2,      // xt as packed bf16x2
                       const int* __restrict__ bcount,
                       const int* __restrict__ bucket,
                       const ushort* __restrict__ cbuf,
                       const float* __restrict__ amp_w,    // (32)
                       const float* __restrict__ w1,       // (64,16)
                       const float* __restrict__ b1,       // (16)
                       const float* __restrict__ gate_w2,  // (33)
                       float* __restrict__ ht,
                       float* __restrict__ gi2, float* __restrict__ gj2) {
    __shared__ int   s_src[CAP];
    __shared__ float s_coef[CAP * 8];
    __shared__ float s_x[8][33];
    __shared__ float s_feat[8][33];
    __shared__ float s_wmT[16 * 65];   // [o][kk], kk<64, padded

    int n = blockIdx.x >> 1;
    int bh = (blockIdx.x & 1) << 3;    // batch offset: 0 or 8
    int tid = threadIdx.x;

    int cnt = bcount[n];
    int deg = cnt < CAP ? cnt : CAP;
    for (int k = tid; k < deg; k += 256) s_src[k] = bucket[n * CAP + k];
    for (int p = tid; p < deg * 8; p += 256) {
        int k = p >> 3, bb = p & 7;
        s_coef[p] = bf2f(cbuf[(n * CAP + k) * 16 + bh + bb]);
    }
    {   // w1 transposed: s_wmT[o][kk] = w1[kk*16+o]
        for (int i = tid; i < 1024; i += 256) s_wmT[(i & 15) * 65 + (i >> 4)] = w1[i];
    }
    {   // self features, full fp32
        int b = tid >> 5, c = tid & 31;
        s_x[b][c] = X[((size_t)(bh + b) * N + n) * 32 + c];
    }
    __syncthreads();

    // Gather: c2 = channel pair, b = local batch, kpar = 2-way k-split
    int c2 = tid & 15;
    int b = tid >> 5;
    int kpar = (tid >> 4) & 1;
    uint rowoff = (uint)(bh + b) * 16 + c2;           // uint idx within node blk
    float acc0 = 0.f, acc1 = 0.f;
    int k = kpar;
    for (; k + 14 < deg; k += 16) {                   // 8 independent loads
        int s0 = s_src[k],      s1 = s_src[k + 2],  s2 = s_src[k + 4],  s3 = s_src[k + 6];
        int s4 = s_src[k + 8],  s5 = s_src[k + 10], s6 = s_src[k + 12], s7 = s_src[k + 14];
        float cc0 = s_coef[k * 8 + b],        cc1 = s_coef[(k + 2) * 8 + b];
        float cc2 = s_coef[(k + 4) * 8 + b],  cc3 = s_coef[(k + 6) * 8 + b];
        float cc4 = s_coef[(k + 8) * 8 + b],  cc5 = s_coef[(k + 10) * 8 + b];
        float cc6 = s_coef[(k + 12) * 8 + b], cc7 = s_coef[(k + 14) * 8 + b];
        uint u0 = xt2[(uint)s0 * 256 + rowoff];
        uint u1 = xt2[(uint)s1 * 256 + rowoff];
        uint u2 = xt2[(uint)s2 * 256 + rowoff];
        uint u3 = xt2[(uint)s3 * 256 + rowoff];
        uint u4 = xt2[(uint)s4 * 256 + rowoff];
        uint u5 = xt2[(uint)s5 * 256 + rowoff];
        uint u6 = xt2[(uint)s6 * 256 + rowoff];
        uint u7 = xt2[(uint)s7 * 256 + rowoff];
        acc0 += cc0 * bf2f_lo(u0) + cc1 * bf2f_lo(u1) + cc2 * bf2f_lo(u2) + cc3 * bf2f_lo(u3)
              + cc4 * bf2f_lo(u4) + cc5 * bf2f_lo(u5) + cc6 * bf2f_lo(u6) + cc7 * bf2f_lo(u7);
        acc1 += cc0 * bf2f_hi(u0) + cc1 * bf2f_hi(u1) + cc2 * bf2f_hi(u2) + cc3 * bf2f_hi(u3)
              + cc4 * bf2f_hi(u4) + cc5 * bf2f_hi(u5) + cc6 * bf2f_hi(u6) + cc7 * bf2f_hi(u7);
    }
    for (; k < deg; k += 2) {
        float cc = s_coef[k * 8 + b];
        uint u = xt2[(uint)s_src[k] * 256 + rowoff];
        acc0 += cc * bf2f_lo(u);
        acc1 += cc * bf2f_hi(u);
    }
    acc0 += __shfl_xor(acc0, 16, 64);   // combine kpar halves (tid bit 4)
    acc1 += __shfl_xor(acc1, 16, 64);
    if (kpar == 0) {
        float inv = 1.0f / fmaxf((float)cnt, 1.0f);
        s_feat[b][2 * c2]     = acc0 * amp_w[2 * c2] * inv;
        s_feat[b][2 * c2 + 1] = acc1 * amp_w[2 * c2 + 1] * inv;
    }
    __syncthreads();

    // Dense 64->16, leaky relu, layer-2 gate dots. Contiguous LDS reads.
    if (tid < 128) {
        int o = tid & 15, bb = tid >> 4;
        const float* wr = &s_wmT[o * 65];
        float d = b1[o];
        #pragma unroll
        for (int kk = 0; kk < 32; ++kk) {
            d += s_x[bb][kk]    * wr[kk];
            d += s_feat[bb][kk] * wr[32 + kk];
        }
        d = d > 0.0f ? d : 0.01f * d;
        int gb = bh + bb;
        ht[((size_t)n * 16 + gb) * 16 + o] = d;
        float pi = d * gate_w2[o];
        float pj = d * gate_w2[16 + o];
        #pragma unroll
        for (int off = 8; off; off >>= 1) {
            pi += __shfl_xor(pi, off, 16);
            pj += __shfl_xor(pj, off, 16);
        }
        if (o == 0) { gi2[n * 16 + gb] = pi; gj2[n * 16 + gb] = pj; }
    }
}

// ---------------------------------------------------------------------------
// Fused layer 2, node split across 2 blocks (8 batches each). 256 threads.
// Gather: 8 lanes x float2 per row, 4-way k-parallel, 4-deep unroll.
// ---------------------------------------------------------------------------
__global__ __launch_bounds__(256)
void agg_dense2_kernel(const float* __restrict__ ht,
                       const int* __restrict__ bcount,
                       const int* __restrict__ bucket,
                       const ushort* __restrict__ cbuf,
                       const float* __restrict__ amp_w,    // (16)
                       const float* __restrict__ w2,       // (32,32)
                       const float* __restrict__ b2,       // (32)
                       float* __restrict__ out) {
    __shared__ int   s_src[CAP];
    __shared__ float s_coef[CAP * 8];
    __shared__ float s_x[8][17];
    __shared__ float s_feat[8][17];
    __shared__ float s_wmT[32 * 33];   // [o][kk], kk<32, padded

    int n = blockIdx.x >> 1;
    int bh = (blockIdx.x & 1) << 3;
    int tid = threadIdx.x;

    int cnt = bcount[n];
    int deg = cnt < CAP ? cnt : CAP;
    for (int k = tid; k < deg; k += 256) s_src[k] = bucket[n * CAP + k];
    for (int p = tid; p < deg * 8; p += 256) {
        int k = p >> 3, bb = p & 7;
        s_coef[p] = bf2f(cbuf[(n * CAP + k) * 16 + bh + bb]);
    }
    for (int i = tid; i < 1024; i += 256) s_wmT[(i & 31) * 33 + (i >> 5)] = w2[i];
    if (tid < 128) {
        int b = tid >> 4, c = tid & 15;
        s_x[b][c] = ht[(size_t)n * 256 + (bh + b) * 16 + c];
    }
    __syncthreads();

    // Gather: c2 = tid&7 (channel pair), b = tid>>5, kpar = (tid>>3)&3
    const float2* hp = (const float2*)ht;
    int c2 = tid & 7;
    int b = tid >> 5;
    int kpar = (tid >> 3) & 3;
    uint rowoff = (uint)(bh + b) * 8 + c2;            // float2 idx within node blk
    float acc0 = 0.f, acc1 = 0.f;
    int k = kpar;
    for (; k + 12 < deg; k += 16) {                   // 4 independent loads
        int s0 = s_src[k], s1 = s_src[k + 4], s2 = s_src[k + 8], s3 = s_src[k + 12];
        float cc0 = s_coef[k * 8 + b],       cc1 = s_coef[(k + 4) * 8 + b];
        float cc2 = s_coef[(k + 8) * 8 + b], cc3 = s_coef[(k + 12) * 8 + b];
        float2 u0 = hp[(uint)s0 * 128 + rowoff];
        float2 u1 = hp[(uint)s1 * 128 + rowoff];
        float2 u2 = hp[(uint)s2 * 128 + rowoff];
        float2 u3 = hp[(uint)s3 * 128 + rowoff];
        acc0 += cc0 * u0.x + cc1 * u1.x + cc2 * u2.x + cc3 * u3.x;
        acc1 += cc0 * u0.y + cc1 * u1.y + cc2 * u2.y + cc3 * u3.y;
    }
    for (; k < deg; k += 4) {
        float cc = s_coef[k * 8 + b];
        float2 u = hp[(uint)s_src[k] * 128 + rowoff];
        acc0 += cc * u.x;
        acc1 += cc * u.y;
    }
    acc0 += __shfl_xor(acc0, 8, 64);    // combine 4 kpar groups (tid bits 3,4)
    acc1 += __shfl_xor(acc1, 8, 64);
    acc0 += __shfl_xor(acc0, 16, 64);
    acc1 += __shfl_xor(acc1, 16, 64);
    if (kpar == 0) {
        float inv = 1.0f / fmaxf((float)cnt, 1.0f);
        s_feat[b][2 * c2]     = acc0 * amp_w[2 * c2] * inv;
        s_feat[b][2 * c2 + 1] = acc1 * amp_w[2 * c2 + 1] * inv;
    }
    __syncthreads();

    // Dense 32->32, out (B,N,32). Contiguous LDS reads.
    int o = tid & 31, bb = tid >> 5;
    const float* wr = &s_wmT[o * 33];
    float d = b2[o];
    #pragma unroll
    for (int kk = 0; kk < 16; ++kk) {
        d += s_x[bb][kk]    * wr[kk];
        d += s_feat[bb][kk] * wr[16 + kk];
    }
    out[((size_t)(bh + bb) * N + n) * 32 + o] = d;
}

// ---------------------------------------------------------------------------
extern "C" void kernel_launch(void* const* d_in, const int* in_sizes, int n_in,
                              void* d_out, int out_size, void* d_ws, size_t ws_size,
                              hipStream_t stream) {
    const float* X       = (const float*)d_in[0];
    const int*   ei1     = (const int*)  d_in[1];   // src=ei1, dst=ei1+E
    const float* ew1     = (const float*)d_in[2];
    const int*   ei2     = (const int*)  d_in[4];
    const float* ew2     = (const float*)d_in[5];
    const float* amp_w1  = (const float*)d_in[7];
    const float* gate_w1 = (const float*)d_in[8];
    const float* gate_b1 = (const float*)d_in[9];
    const float* w1      = (const float*)d_in[10];
    const float* b1      = (const float*)d_in[11];
    const float* amp_w2  = (const float*)d_in[12];
    const float* gate_w2 = (const float*)d_in[13];
    const float* gate_b2 = (const float*)d_in[14];
    const float* w2      = (const float*)d_in[15];
    const float* b2      = (const float*)d_in[16];
    float* out = (float*)d_out;

    // ws layout (~62.8 MB)
    char* p = (char*)d_ws;
    ushort* xt     = (ushort*)p; p += (size_t)N * B * 32 * sizeof(ushort); // 10.24 MB
    float* ht      = (float*)p;  p += (size_t)N * B * 16 * sizeof(float);  // 10.24 MB
    float* gi1     = (float*)p;  p += (size_t)N * B * sizeof(float);
    float* gj1     = (float*)p;  p += (size_t)N * B * sizeof(float);
    float* gi2     = (float*)p;  p += (size_t)N * B * sizeof(float);
    float* gj2     = (float*)p;  p += (size_t)N * B * sizeof(float);
    int*   bucket1 = (int*)p;    p += (size_t)N * CAP * sizeof(int);       // 3.84 MB
    int*   bucket2 = (int*)p;    p += (size_t)N * CAP * sizeof(int);       // 3.84 MB
    int*   slot1   = (int*)p;    p += (size_t)E * sizeof(int);             // 0.64 MB
    int*   slot2   = (int*)p;    p += (size_t)E * sizeof(int);             // 0.64 MB
    int*   bcount1 = (int*)p;    p += (size_t)N * sizeof(int);
    int*   bcount2 = (int*)p;    p += (size_t)N * sizeof(int);
    ushort* cbuf   = (ushort*)p; p += (size_t)N * CAP * 16 * sizeof(ushort); // 30.72 MB

    hipMemsetAsync(bcount1, 0, 2 * (size_t)N * sizeof(int), stream);
    bucket_kernel<<<(2 * E + 255) / 256, 256, 0, stream>>>(
        ei1, ei2, bcount1, bucket1, slot1, bcount2, bucket2, slot2);
    prep_kernel<<<(N * B * 32 + 255) / 256, 256, 0, stream>>>(X, gate_w1, xt, gi1, gj1);

    coef_kernel<<<(E * 16 + 255) / 256, 256, 0, stream>>>(
        ei1, ei1 + E, ew1, gi1, gj1, slot1, gate_w1, 64, gate_b1, cbuf);

    agg_dense1_kernel<<<2 * N, 256, 0, stream>>>(
        X, (const uint*)xt, bcount1, bucket1, cbuf,
        amp_w1, w1, b1, gate_w2, ht, gi2, gj2);

    coef_kernel<<<(E * 16 + 255) / 256, 256, 0, stream>>>(
        ei2, ei2 + E, ew2, gi2, gj2, slot2, gate_w2, 32, gate_b2, cbuf);

    agg_dense2_kernel<<<2 * N, 256, 0, stream>>>(
        ht, bcount2, bucket2, cbuf, amp_w2, w2, b2, out);
}

// Round 7
// 219.072 us; speedup vs baseline: 1.1865x; 1.1865x over previous
//
#include <hip/hip_runtime.h>
#include <math.h>

#define B 16
#define N 10000
#define E 160000
#define CAP 96   // per-dst bucket capacity; deg ~ Poisson(16), P(deg>96) ~ 0

// float -> bf16 (RNE) stored as ushort
__device__ __forceinline__ ushort f2bf(float v) {
    uint u = __float_as_uint(v);
    u = (u + 0x7fffu + ((u >> 16) & 1u)) >> 16;
    return (ushort)u;
}
__device__ __forceinline__ float bf2f_lo(uint u) { return __uint_as_float(u << 16); }
__device__ __forceinline__ float bf2f_hi(uint u) { return __uint_as_float(u & 0xffff0000u); }

// ---------------------------------------------------------------------------
// Prep: X (B,N,32) fp32 -> xt (N,B,32) bf16, plus layer-1 gate dots (fp32).
// ---------------------------------------------------------------------------
__global__ void prep_kernel(const float* __restrict__ X,
                            const float* __restrict__ gate_w,   // (65)
                            ushort* __restrict__ xt,
                            float* __restrict__ gi, float* __restrict__ gj) {
    int t = blockIdx.x * blockDim.x + threadIdx.x;
    if (t >= N * B * 32) return;
    int c = t & 31;
    int r = t >> 5;            // n*B + b
    int b = r & 15;
    int n = r >> 4;
    float v = X[((size_t)b * N + n) * 32 + c];
    xt[t] = f2bf(v);
    float pi = v * gate_w[c];
    float pj = v * gate_w[32 + c];
    #pragma unroll
    for (int off = 16; off; off >>= 1) {
        pi += __shfl_xor(pi, off, 32);
        pj += __shfl_xor(pj, off, 32);
    }
    if (c == 0) { gi[r] = pi; gj[r] = pj; }
}

// ---------------------------------------------------------------------------
// Bucket both graphs: payload (src, ew-bits), bcount = exact degree.
// ---------------------------------------------------------------------------
__global__ void bucket_kernel(const int* __restrict__ ei1, const float* __restrict__ ew1,
                              const int* __restrict__ ei2, const float* __restrict__ ew2,
                              int* __restrict__ bcount1, int2* __restrict__ bucket1,
                              int* __restrict__ bcount2, int2* __restrict__ bucket2) {
    int t = blockIdx.x * blockDim.x + threadIdx.x;
    if (t < E) {
        int d = ei1[E + t];
        int pos = atomicAdd(&bcount1[d], 1);
        if (pos < CAP) bucket1[d * CAP + pos] = make_int2(ei1[t], __float_as_int(ew1[t]));
    } else if (t < 2 * E) {
        int e = t - E;
        int d = ei2[E + e];
        int pos = atomicAdd(&bcount2[d], 1);
        if (pos < CAP) bucket2[d * CAP + pos] = make_int2(ei2[e], __float_as_int(ew2[e]));
    }
}

// ---------------------------------------------------------------------------
// Fused layer 1: one node per block, 256 threads = 4 waves.
// Gather: one slot per wave-iteration; lane l -> (b=l/4, q=l%4) dwordx4 =
// whole 1KB node block per wave instruction.
// ---------------------------------------------------------------------------
__global__ __launch_bounds__(256, 6)
void agg_dense1_kernel(const float* __restrict__ X,
                       const uint4* __restrict__ xt4,     // xt as uint4 (16B=8ch)
                       const float* __restrict__ gi,
                       const float* __restrict__ gj,
                       const int* __restrict__ bcount,
                       const int2* __restrict__ bucket,
                       const float* __restrict__ gate_w,   // (65), [64]=wge
                       const float* __restrict__ gate_b,
                       const float* __restrict__ amp_w,    // (32)
                       const float* __restrict__ w1,       // (64,16)
                       const float* __restrict__ b1,       // (16)
                       const float* __restrict__ gate_w2,  // (33)
                       float* __restrict__ ht,
                       float* __restrict__ gi2, float* __restrict__ gj2) {
    __shared__ int2  s_eb[CAP];          // (src, ew)
    __shared__ float s_coef[CAP * 16];   // 6 KB
    __shared__ float s_gi[16];
    __shared__ float s_part[4][16][33];  // 8.4 KB, padded
    __shared__ float s_x[16][33];
    __shared__ float s_feat[16][33];
    __shared__ float s_wmT[16 * 65];     // [o][kk]

    int n = blockIdx.x;
    int tid = threadIdx.x;

    int cnt = bcount[n];
    int deg = cnt < CAP ? cnt : CAP;
    if (tid < deg) s_eb[tid] = bucket[n * CAP + tid];
    for (int i = tid; i < 1024; i += 256) s_wmT[(i & 15) * 65 + (i >> 4)] = w1[i];
    for (int i = tid; i < 512; i += 256) {
        int b = i >> 5, c = i & 31;
        s_x[b][c] = X[((size_t)b * N + n) * 32 + c];
    }
    if (tid < 16) s_gi[tid] = gi[n * 16 + tid] + gate_b[0];
    __syncthreads();

    // Phase 1: coef[k][b] = ew * sigmoid(gi + gj + ew*wge + gb). Edge-parallel.
    float wge = gate_w[64];
    for (int p = tid; p < deg * 16; p += 256) {
        int k = p >> 4, b = p & 15;
        int2 pr = s_eb[k];
        float w = __int_as_float(pr.y);
        float z = s_gi[b] + gj[pr.x * 16 + b] + w * wge;
        s_coef[p] = w / (1.0f + __expf(-z));
    }
    __syncthreads();

    // Phase 2: gather. wave w owns slots w, w+4, ... (4-unrolled -> stride 16).
    int wv = tid >> 6, l = tid & 63;
    int b = l >> 2, q = l & 3;
    uint boff = (uint)b * 4 + q;               // uint4 idx within 1KB node block
    float a0 = 0.f, a1 = 0.f, a2 = 0.f, a3 = 0.f, a4 = 0.f, a5 = 0.f, a6 = 0.f, a7 = 0.f;
    int k = wv;
    for (; k + 12 < deg; k += 16) {
        int sA = s_eb[k].x,      sB = s_eb[k + 4].x;
        int sC = s_eb[k + 8].x,  sD = s_eb[k + 12].x;
        float cA = s_coef[(k << 4) | b],       cB = s_coef[((k + 4) << 4) | b];
        float cC = s_coef[((k + 8) << 4) | b], cD = s_coef[((k + 12) << 4) | b];
        uint4 uA = xt4[(uint)sA * 64 + boff];
        uint4 uB = xt4[(uint)sB * 64 + boff];
        uint4 uC = xt4[(uint)sC * 64 + boff];
        uint4 uD = xt4[(uint)sD * 64 + boff];
        a0 += cA * bf2f_lo(uA.x) + cB * bf2f_lo(uB.x) + cC * bf2f_lo(uC.x) + cD * bf2f_lo(uD.x);
        a1 += cA * bf2f_hi(uA.x) + cB * bf2f_hi(uB.x) + cC * bf2f_hi(uC.x) + cD * bf2f_hi(uD.x);
        a2 += cA * bf2f_lo(uA.y) + cB * bf2f_lo(uB.y) + cC * bf2f_lo(uC.y) + cD * bf2f_lo(uD.y);
        a3 += cA * bf2f_hi(uA.y) + cB * bf2f_hi(uB.y) + cC * bf2f_hi(uC.y) + cD * bf2f_hi(uD.y);
        a4 += cA * bf2f_lo(uA.z) + cB * bf2f_lo(uB.z) + cC * bf2f_lo(uC.z) + cD * bf2f_lo(uD.z);
        a5 += cA * bf2f_hi(uA.z) + cB * bf2f_hi(uB.z) + cC * bf2f_hi(uC.z) + cD * bf2f_hi(uD.z);
        a6 += cA * bf2f_lo(uA.w) + cB * bf2f_lo(uB.w) + cC * bf2f_lo(uC.w) + cD * bf2f_lo(uD.w);
        a7 += cA * bf2f_hi(uA.w) + cB * bf2f_hi(uB.w) + cC * bf2f_hi(uC.w) + cD * bf2f_hi(uD.w);
    }
    for (; k < deg; k += 4) {
        int s = s_eb[k].x;
        float cc = s_coef[(k << 4) | b];
        uint4 u = xt4[(uint)s * 64 + boff];
        a0 += cc * bf2f_lo(u.x); a1 += cc * bf2f_hi(u.x);
        a2 += cc * bf2f_lo(u.y); a3 += cc * bf2f_hi(u.y);
        a4 += cc * bf2f_lo(u.z); a5 += cc * bf2f_hi(u.z);
        a6 += cc * bf2f_lo(u.w); a7 += cc * bf2f_hi(u.w);
    }
    {
        float* pp = &s_part[wv][b][q * 8];
        pp[0] = a0; pp[1] = a1; pp[2] = a2; pp[3] = a3;
        pp[4] = a4; pp[5] = a5; pp[6] = a6; pp[7] = a7;
    }
    __syncthreads();

    // Phase 3: reduce partials, apply amp_w / mean.
    float inv = 1.0f / fmaxf((float)cnt, 1.0f);
    for (int i = tid; i < 512; i += 256) {
        int bb = i >> 5, c = i & 31;
        float f = s_part[0][bb][c] + s_part[1][bb][c] + s_part[2][bb][c] + s_part[3][bb][c];
        s_feat[bb][c] = f * amp_w[c] * inv;
    }
    __syncthreads();

    // Phase 4: dense 64->16, leaky relu, layer-2 gate dots. 256 thr = 16b x 16o.
    {
        int o = tid & 15, bb = tid >> 4;
        const float* wr = &s_wmT[o * 65];
        float d = b1[o];
        #pragma unroll
        for (int kk = 0; kk < 32; ++kk) {
            d += s_x[bb][kk]    * wr[kk];
            d += s_feat[bb][kk] * wr[32 + kk];
        }
        d = d > 0.0f ? d : 0.01f * d;
        ht[((size_t)n * 16 + bb) * 16 + o] = d;
        float pi = d * gate_w2[o];
        float pj = d * gate_w2[16 + o];
        #pragma unroll
        for (int off = 8; off; off >>= 1) {
            pi += __shfl_xor(pi, off, 16);
            pj += __shfl_xor(pj, off, 16);
        }
        if (o == 0) { gi2[n * 16 + bb] = pi; gj2[n * 16 + bb] = pj; }
    }
}

// ---------------------------------------------------------------------------
// Fused layer 2: one node per block, 256 threads = 4 waves.
// ht node block = 16b x 16ch fp32 = 1KB; lane l -> (b=l/4, q=l%4) float4.
// ---------------------------------------------------------------------------
__global__ __launch_bounds__(256, 6)
void agg_dense2_kernel(const float* __restrict__ ht,
                       const float4* __restrict__ ht4,
                       const float* __restrict__ gi,
                       const float* __restrict__ gj,
                       const int* __restrict__ bcount,
                       const int2* __restrict__ bucket,
                       const float* __restrict__ gate_w,   // (33), [32]=wge
                       const float* __restrict__ gate_b,
                       const float* __restrict__ amp_w,    // (16)
                       const float* __restrict__ w2,       // (32,32)
                       const float* __restrict__ b2,       // (32)
                       float* __restrict__ out) {
    __shared__ int2  s_eb[CAP];
    __shared__ float s_coef[CAP * 16];
    __shared__ float s_gi[16];
    __shared__ float s_part[4][16][17];  // 4.4 KB
    __shared__ float s_x[16][17];
    __shared__ float s_feat[16][17];
    __shared__ float s_wmT[32 * 33];

    int n = blockIdx.x;
    int tid = threadIdx.x;

    int cnt = bcount[n];
    int deg = cnt < CAP ? cnt : CAP;
    if (tid < deg) s_eb[tid] = bucket[n * CAP + tid];
    for (int i = tid; i < 1024; i += 256) s_wmT[(i & 31) * 33 + (i >> 5)] = w2[i];
    {
        int b = tid >> 4, c = tid & 15;
        s_x[b][c] = ht[(size_t)n * 256 + b * 16 + c];
    }
    if (tid < 16) s_gi[tid] = gi[n * 16 + tid] + gate_b[0];
    __syncthreads();

    float wge = gate_w[32];
    for (int p = tid; p < deg * 16; p += 256) {
        int k = p >> 4, b = p & 15;
        int2 pr = s_eb[k];
        float w = __int_as_float(pr.y);
        float z = s_gi[b] + gj[pr.x * 16 + b] + w * wge;
        s_coef[p] = w / (1.0f + __expf(-z));
    }
    __syncthreads();

    int wv = tid >> 6, l = tid & 63;
    int b = l >> 2, q = l & 3;
    uint boff = (uint)b * 4 + q;               // float4 idx within 1KB node block
    float a0 = 0.f, a1 = 0.f, a2 = 0.f, a3 = 0.f;
    int k = wv;
    for (; k + 12 < deg; k += 16) {
        int sA = s_eb[k].x,      sB = s_eb[k + 4].x;
        int sC = s_eb[k + 8].x,  sD = s_eb[k + 12].x;
        float cA = s_coef[(k << 4) | b],       cB = s_coef[((k + 4) << 4) | b];
        float cC = s_coef[((k + 8) << 4) | b], cD = s_coef[((k + 12) << 4) | b];
        float4 uA = ht4[(uint)sA * 64 + boff];
        float4 uB = ht4[(uint)sB * 64 + boff];
        float4 uC = ht4[(uint)sC * 64 + boff];
        float4 uD = ht4[(uint)sD * 64 + boff];
        a0 += cA * uA.x + cB * uB.x + cC * uC.x + cD * uD.x;
        a1 += cA * uA.y + cB * uB.y + cC * uC.y + cD * uD.y;
        a2 += cA * uA.z + cB * uB.z + cC * uC.z + cD * uD.z;
        a3 += cA * uA.w + cB * uB.w + cC * uC.w + cD * uD.w;
    }
    for (; k < deg; k += 4) {
        int s = s_eb[k].x;
        float cc = s_coef[(k << 4) | b];
        float4 u = ht4[(uint)s * 64 + boff];
        a0 += cc * u.x; a1 += cc * u.y; a2 += cc * u.z; a3 += cc * u.w;
    }
    {
        float* pp = &s_part[wv][b][q * 4];
        pp[0] = a0; pp[1] = a1; pp[2] = a2; pp[3] = a3;
    }
    __syncthreads();

    float inv = 1.0f / fmaxf((float)cnt, 1.0f);
    {
        int bb = tid >> 4, c = tid & 15;
        float f = s_part[0][bb][c] + s_part[1][bb][c] + s_part[2][bb][c] + s_part[3][bb][c];
        s_feat[bb][c] = f * amp_w[c] * inv;
    }
    __syncthreads();

    // Dense 32->32; thread produces (o, o+16). out (B,N,32).
    int o = tid & 15, bb = tid >> 4;
    const float* wr0 = &s_wmT[o * 33];
    const float* wr1 = &s_wmT[(o + 16) * 33];
    float d0 = b2[o], d1 = b2[o + 16];
    #pragma unroll
    for (int kk = 0; kk < 16; ++kk) {
        float xv = s_x[bb][kk], fv = s_feat[bb][kk];
        d0 += xv * wr0[kk] + fv * wr0[16 + kk];
        d1 += xv * wr1[kk] + fv * wr1[16 + kk];
    }
    size_t ob = ((size_t)bb * N + n) * 32;
    out[ob + o] = d0;
    out[ob + o + 16] = d1;
}

// ---------------------------------------------------------------------------
extern "C" void kernel_launch(void* const* d_in, const int* in_sizes, int n_in,
                              void* d_out, int out_size, void* d_ws, size_t ws_size,
                              hipStream_t stream) {
    const float* X       = (const float*)d_in[0];
    const int*   ei1     = (const int*)  d_in[1];   // src=ei1, dst=ei1+E
    const float* ew1     = (const float*)d_in[2];
    const int*   ei2     = (const int*)  d_in[4];
    const float* ew2     = (const float*)d_in[5];
    const float* amp_w1  = (const float*)d_in[7];
    const float* gate_w1 = (const float*)d_in[8];
    const float* gate_b1 = (const float*)d_in[9];
    const float* w1      = (const float*)d_in[10];
    const float* b1      = (const float*)d_in[11];
    const float* amp_w2  = (const float*)d_in[12];
    const float* gate_w2 = (const float*)d_in[13];
    const float* gate_b2 = (const float*)d_in[14];
    const float* w2      = (const float*)d_in[15];
    const float* b2      = (const float*)d_in[16];
    float* out = (float*)d_out;

    // ws layout
    char* p = (char*)d_ws;
    ushort* xt     = (ushort*)p; p += (size_t)N * B * 32 * sizeof(ushort); // 10.24 MB
    float* ht      = (float*)p;  p += (size_t)N * B * 16 * sizeof(float);  // 10.24 MB
    float* gi1     = (float*)p;  p += (size_t)N * B * sizeof(float);
    float* gj1     = (float*)p;  p += (size_t)N * B * sizeof(float);
    float* gi2     = (float*)p;  p += (size_t)N * B * sizeof(float);
    float* gj2     = (float*)p;  p += (size_t)N * B * sizeof(float);
    int2*  bucket1 = (int2*)p;   p += (size_t)N * CAP * sizeof(int2);      // 7.68 MB
    int2*  bucket2 = (int2*)p;   p += (size_t)N * CAP * sizeof(int2);      // 7.68 MB
    int*   bcount1 = (int*)p;    p += (size_t)N * sizeof(int);
    int*   bcount2 = (int*)p;    p += (size_t)N * sizeof(int);

    hipMemsetAsync(bcount1, 0, 2 * (size_t)N * sizeof(int), stream);
    bucket_kernel<<<(2 * E + 255) / 256, 256, 0, stream>>>(
        ei1, ew1, ei2, ew2, bcount1, bucket1, bcount2, bucket2);
    prep_kernel<<<(N * B * 32 + 255) / 256, 256, 0, stream>>>(X, gate_w1, xt, gi1, gj1);

    agg_dense1_kernel<<<N, 256, 0, stream>>>(
        X, (const uint4*)xt, gi1, gj1, bcount1, bucket1,
        gate_w1, gate_b1, amp_w1, w1, b1, gate_w2, ht, gi2, gj2);

    agg_dense2_kernel<<<N, 256, 0, stream>>>(
        ht, (const float4*)ht, gi2, gj2, bcount2, bucket2,
        gate_w2, gate_b2, amp_w2, w2, b2, out);
}